// Round 7
// baseline (58.553 us; speedup 1.0000x reference)
//
#include <hip/hip_runtime.h>
#include <math.h>

#define NQ 4
#define NL 6
#define BATCH 524288
#define EPT 4  // elements per thread

struct C2 { float re, im; };

__device__ __forceinline__ C2 cmul(C2 a, C2 b) {
    return C2{ __builtin_fmaf(a.re, b.re, -a.im * b.im),
               __builtin_fmaf(a.re, b.im,  a.im * b.re) };
}

// ---------------------------------------------------------------------------
// Single fused kernel (one graph node — R1..R6 fit a ~20us inter-node gap for
// two-kernel graphs, so fusion is the lever; bodies are only ~5-7us).
// Per block (256 thr, EPT=4, 512 blocks):
//   0) ALL threads: coalesced x loads + sincos + Kronecker m[4][16] (regs)
//      -- independent of V, overlaps wave0's serial V-build chain.
//   1) wave0 lanes 0..23: fused U = RZ*RY*RX gates -> sU        (barrier)
//   2) wave0 lanes 0..31: evolve 16 basis columns through 6 layers
//      (lane = 2j+h; 8 complex amps in regs; cross-half via __shfl_xor),
//      fold (-i)^popcount(j), write V -> sV4                     (barrier)
//   3) ALL threads: psi = V*m (LDS float4 broadcasts, row regs amortized
//      over 4 elements), ev_q = sum_r z_q(r)|psi_r|^2, coalesced store.
// ---------------------------------------------------------------------------
__global__ __launch_bounds__(256) void qall_kernel(const float4* __restrict__ x,
                                                   const float* __restrict__ w,
                                                   float4* __restrict__ out) {
    __shared__ float sU[NL * NQ * 8];
    __shared__ float4 sV4[128];  // 16 rows x 8 float4 (float4 = 2 cols' re,im)

    const int tid = threadIdx.x;
    const int base = blockIdx.x * (256 * EPT) + tid;

    // ---- 0) per-element Kronecker vectors (all threads, before barriers) ----
    float m[EPT][16];
#pragma unroll
    for (int e = 0; e < EPT; ++e) {
        const float4 xv = x[base + e * 256];
        float c0, s0, c1, s1, c2, s2, c3, s3;
        __sincosf(0.5f * xv.x, &s0, &c0);
        __sincosf(0.5f * xv.y, &s1, &c1);
        __sincosf(0.5f * xv.z, &s2, &c2);
        __sincosf(0.5f * xv.w, &s3, &c3);
        float ab[4];
        ab[0] = c0 * c1; ab[1] = c0 * s1; ab[2] = s0 * c1; ab[3] = s0 * s1;
        float abc[8];
#pragma unroll
        for (int k = 0; k < 4; ++k) { abc[2 * k] = ab[k] * c2; abc[2 * k + 1] = ab[k] * s2; }
#pragma unroll
        for (int k = 0; k < 8; ++k) { m[e][2 * k] = abc[k] * c3; m[e][2 * k + 1] = abc[k] * s3; }
    }

    // ---- 1) fused gate matrices (wave0 lanes 0..23) ----
    if (tid < NL * NQ) {
        const float a = w[tid * 3 + 0];
        const float b = w[tid * 3 + 1];
        const float g = w[tid * 3 + 2];
        float ca, sa, cb, sb, cg, sg;
        sincosf(0.5f * a, &sa, &ca);
        sincosf(0.5f * b, &sb, &cb);
        sincosf(0.5f * g, &sg, &cg);
        C2 M00{cb * ca,  sb * sa};
        C2 M01{-sb * ca, -cb * sa};
        C2 M10{sb * ca,  -cb * sa};
        C2 M11{cb * ca,  -sb * sa};
        C2 em{cg, -sg}, ep{cg, sg};
        C2 U00 = cmul(em, M00), U01 = cmul(em, M01);
        C2 U10 = cmul(ep, M10), U11 = cmul(ep, M11);
        float* o = &sU[tid * 8];
        o[0] = U00.re; o[1] = U00.im; o[2] = U01.re; o[3] = U01.im;
        o[4] = U10.re; o[5] = U10.im; o[6] = U11.re; o[7] = U11.im;
    }
    __syncthreads();

    // ---- 2) evolve basis columns (wave0 lanes 0..31) ----
    if (tid < 32) {
        const int j = tid >> 1;   // column
        const int h = tid & 1;    // bit3 of rows owned

        C2 st[8];
#pragma unroll
        for (int i = 0; i < 8; ++i) st[i] = C2{0.f, 0.f};
        if ((j >> 3) == h) st[j & 7].re = 1.f;

#define APPLY_PAIR(i0, i1)                                                     \
    {                                                                          \
        C2 a0 = st[i0], a1 = st[i1];                                           \
        st[i0].re = U00.re*a0.re - U00.im*a0.im + U01.re*a1.re - U01.im*a1.im; \
        st[i0].im = U00.re*a0.im + U00.im*a0.re + U01.re*a1.im + U01.im*a1.re; \
        st[i1].re = U10.re*a0.re - U10.im*a0.im + U11.re*a1.re - U11.im*a1.im; \
        st[i1].im = U10.re*a0.im + U10.im*a0.re + U11.re*a1.im + U11.im*a1.re; \
    }
#define SWAPST(a, b) { C2 t_ = st[a]; st[a] = st[b]; st[b] = t_; }

#pragma unroll
        for (int l = 0; l < NL; ++l) {
            {   // CNOT(q0 mask8, q1 mask4): if h==1, permute i <-> i^4
                C2 ns[8];
#pragma unroll
                for (int i = 0; i < 8; ++i) {
                    ns[i].re = h ? st[i ^ 4].re : st[i].re;
                    ns[i].im = h ? st[i ^ 4].im : st[i].im;
                }
#pragma unroll
                for (int i = 0; i < 8; ++i) st[i] = ns[i];
            }
            SWAPST(4, 6) SWAPST(5, 7)           // CNOT(q1, q2)
            SWAPST(2, 3) SWAPST(6, 7)           // CNOT(q2, q3)
#pragma unroll
            for (int i = 1; i < 8; i += 2) {    // CNOT(q3, q0)
                st[i].re = __shfl_xor(st[i].re, 1);
                st[i].im = __shfl_xor(st[i].im, 1);
            }
            {   // qubit 0 gate (cross-lane)
                const float* u = &sU[(l * NQ + 0) * 8];
                C2 U00{u[0], u[1]}, U01{u[2], u[3]}, U10{u[4], u[5]}, U11{u[6], u[7]};
                C2 Ud = h ? U11 : U00;
                C2 Uo = h ? U10 : U01;
#pragma unroll
                for (int i = 0; i < 8; ++i) {
                    C2 p{__shfl_xor(st[i].re, 1), __shfl_xor(st[i].im, 1)};
                    C2 a = st[i];
                    st[i].re = Ud.re*a.re - Ud.im*a.im + Uo.re*p.re - Uo.im*p.im;
                    st[i].im = Ud.re*a.im + Ud.im*a.re + Uo.re*p.im + Uo.im*p.re;
                }
            }
            {   // qubit 1 gate
                const float* u = &sU[(l * NQ + 1) * 8];
                C2 U00{u[0], u[1]}, U01{u[2], u[3]}, U10{u[4], u[5]}, U11{u[6], u[7]};
                APPLY_PAIR(0, 4) APPLY_PAIR(1, 5) APPLY_PAIR(2, 6) APPLY_PAIR(3, 7)
            }
            {   // qubit 2 gate
                const float* u = &sU[(l * NQ + 2) * 8];
                C2 U00{u[0], u[1]}, U01{u[2], u[3]}, U10{u[4], u[5]}, U11{u[6], u[7]};
                APPLY_PAIR(0, 2) APPLY_PAIR(1, 3) APPLY_PAIR(4, 6) APPLY_PAIR(5, 7)
            }
            {   // qubit 3 gate
                const float* u = &sU[(l * NQ + 3) * 8];
                C2 U00{u[0], u[1]}, U01{u[2], u[3]}, U10{u[4], u[5]}, U11{u[6], u[7]};
                APPLY_PAIR(0, 1) APPLY_PAIR(2, 3) APPLY_PAIR(4, 5) APPLY_PAIR(6, 7)
            }
        }

        // fold (-i)^popcount(j); V[r][j] -> sV4 layout [r*8 + j/2].{xy|zw}
        const int p4 = __popc(j) & 3;
        const float fr = (p4 == 0) ? 1.f : (p4 == 2) ? -1.f : 0.f;
        const float fi = (p4 == 1) ? -1.f : (p4 == 3) ? 1.f : 0.f;
        float* sVf = reinterpret_cast<float*>(sV4);
#pragma unroll
        for (int i = 0; i < 8; ++i) {
            const int r = h * 8 + i;
            const float re = st[i].re * fr - st[i].im * fi;
            const float im = st[i].re * fi + st[i].im * fr;
            reinterpret_cast<float2*>(&sVf[r * 32 + 2 * j])[0] = make_float2(re, im);
        }
#undef APPLY_PAIR
#undef SWAPST
    }
    __syncthreads();

    // ---- 3) batched matvec + expectation values ----
    float ev[EPT][4];
#pragma unroll
    for (int e = 0; e < EPT; ++e)
#pragma unroll
        for (int q = 0; q < 4; ++q) ev[e][q] = 0.f;

#pragma unroll
    for (int r = 0; r < 16; ++r) {
        float4 row[8];
#pragma unroll
        for (int k = 0; k < 8; ++k) row[k] = sV4[r * 8 + k];
#pragma unroll
        for (int e = 0; e < EPT; ++e) {
            float re = 0.f, im = 0.f;
#pragma unroll
            for (int k = 0; k < 8; ++k) {
                re = __builtin_fmaf(m[e][2 * k],     row[k].x, re);
                im = __builtin_fmaf(m[e][2 * k],     row[k].y, im);
                re = __builtin_fmaf(m[e][2 * k + 1], row[k].z, re);
                im = __builtin_fmaf(m[e][2 * k + 1], row[k].w, im);
            }
            const float p = __builtin_fmaf(re, re, im * im);
            if (r & 8) ev[e][0] -= p; else ev[e][0] += p;
            if (r & 4) ev[e][1] -= p; else ev[e][1] += p;
            if (r & 2) ev[e][2] -= p; else ev[e][2] += p;
            if (r & 1) ev[e][3] -= p; else ev[e][3] += p;
        }
    }

#pragma unroll
    for (int e = 0; e < EPT; ++e) {
        out[base + e * 256] = make_float4(ev[e][0], ev[e][1], ev[e][2], ev[e][3]);
    }
}

extern "C" void kernel_launch(void* const* d_in, const int* in_sizes, int n_in,
                              void* d_out, int out_size, void* d_ws, size_t ws_size,
                              hipStream_t stream) {
    const float4* x = (const float4*)d_in[0];   // [B,4] f32
    const float*  w = (const float*)d_in[1];    // [6,4,3] f32
    float4* out = (float4*)d_out;               // [B,4] f32

    const int blocks = BATCH / (256 * EPT);     // 512
    qall_kernel<<<blocks, 256, 0, stream>>>(x, w, out);
}

// Round 9
// 19.188 us; speedup vs baseline: 3.0515x; 3.0515x over previous
//
#include <hip/hip_runtime.h>
#include <math.h>

#define NQ 4
#define NL 6
#define BATCH 524288
#define EPT 4
#define LP 17   // padded row stride (float2) to break bank aliasing on row reads

struct C2 { float re, im; };

__device__ __forceinline__ C2 cmul(C2 a, C2 b) {
    return C2{ __builtin_fmaf(a.re, b.re, -a.im * b.im),
               __builtin_fmaf(a.re, b.im,  a.im * b.re) };
}

// ---------------------------------------------------------------------------
// ONE kernel, one graph node. Per block (256 thr, EPT=4, 512 blocks):
//   0) all threads: x loads + sincos + Kronecker m[4][16]   (regs, no LDS)
//   1) tid<24: fused U = RZ*RY*RX 2x2 gates -> sU                [barrier]
//   2) LAYER MATRICES, 256-wide (replaces the ~18us serial 32-lane chain
//      measured in R3/R7): thread (r,c) computes, for l = 0..5,
//        L_l[r][c] = prod_q U_q[r_q][perm(c)_q],
//      where perm = CNOT ladder as a classical bit map.          [barrier]
//   3) tree matmul (all 256 threads, 16 cmul/entry/stage):
//        A=L1*L0, B=L3*L2, C=L5*L4   [barrier]   D=B*A   [barrier]
//        V=C*D, fold (-i)^popcount(c), pack -> sV4               [barrier]
//   4) matvec + expectation values (verbatim proven R2 path), store.
// ---------------------------------------------------------------------------
__global__ __launch_bounds__(256) void qone_kernel(const float4* __restrict__ x,
                                                   const float* __restrict__ w,
                                                   float4* __restrict__ out) {
    __shared__ float  sU[NL * NQ * 8];       // 768 B
    __shared__ float2 sL[NL][16 * LP];       // 6 layer matrices, padded
    __shared__ float2 sP[3][16 * LP];        // A, B, C
    __shared__ float2 sD[16 * LP];           // D = B*A
    __shared__ float4 sV4[128];              // final V, matvec layout

    const int tid = threadIdx.x;
    const int base = blockIdx.x * (256 * EPT) + tid;

    // ---- 0) per-element Kronecker vectors ----
    float m[EPT][16];
#pragma unroll
    for (int e = 0; e < EPT; ++e) {
        const float4 xv = x[base + e * 256];
        float c0, s0, c1, s1, c2, s2, c3, s3;
        __sincosf(0.5f * xv.x, &s0, &c0);
        __sincosf(0.5f * xv.y, &s1, &c1);
        __sincosf(0.5f * xv.z, &s2, &c2);
        __sincosf(0.5f * xv.w, &s3, &c3);
        float ab[4];
        ab[0] = c0 * c1; ab[1] = c0 * s1; ab[2] = s0 * c1; ab[3] = s0 * s1;
        float abc[8];
#pragma unroll
        for (int k = 0; k < 4; ++k) { abc[2 * k] = ab[k] * c2; abc[2 * k + 1] = ab[k] * s2; }
#pragma unroll
        for (int k = 0; k < 8; ++k) { m[e][2 * k] = abc[k] * c3; m[e][2 * k + 1] = abc[k] * s3; }
    }

    // ---- 1) fused gate matrices (24 threads, parallel, precise sincosf) ----
    if (tid < NL * NQ) {
        const float a = w[tid * 3 + 0];
        const float b = w[tid * 3 + 1];
        const float g = w[tid * 3 + 2];
        float ca, sa, cb, sb, cg, sg;
        sincosf(0.5f * a, &sa, &ca);
        sincosf(0.5f * b, &sb, &cb);
        sincosf(0.5f * g, &sg, &cg);
        C2 M00{cb * ca,  sb * sa};
        C2 M01{-sb * ca, -cb * sa};
        C2 M10{sb * ca,  -cb * sa};
        C2 M11{cb * ca,  -sb * sa};
        C2 em{cg, -sg}, ep{cg, sg};
        C2 U00 = cmul(em, M00), U01 = cmul(em, M01);
        C2 U10 = cmul(ep, M10), U11 = cmul(ep, M11);
        float* o = &sU[tid * 8];
        o[0] = U00.re; o[1] = U00.im; o[2] = U01.re; o[3] = U01.im;
        o[4] = U10.re; o[5] = U10.im; o[6] = U11.re; o[7] = U11.im;
    }
    __syncthreads();

    const int r = tid >> 4;       // output row 0..15
    const int c = tid & 15;       // output col 0..15

    // ---- 2) layer matrices: L_l[r][c] = prod_q U_q[r_q][perm(c)_q] ----
    {
        // perm(c): CNOT(0,1),(1,2),(2,3),(3,0) applied in order (bit0=q0=mask8)
        int b0 = (c >> 3) & 1, b1 = (c >> 2) & 1, b2 = (c >> 1) & 1, b3 = c & 1;
        b1 ^= b0; b2 ^= b1; b3 ^= b2; b0 ^= b3;
        const int r0 = (r >> 3) & 1, r1 = (r >> 2) & 1, r2 = (r >> 1) & 1, r3 = r & 1;
        const int o0 = (r0 * 2 + b0) * 2;
        const int o1 = (r1 * 2 + b1) * 2;
        const int o2 = (r2 * 2 + b2) * 2;
        const int o3 = (r3 * 2 + b3) * 2;
#pragma unroll
        for (int l = 0; l < NL; ++l) {
            const float* g = &sU[l * 32];
            C2 a{g[o0], g[o0 + 1]};
            a = cmul(a, C2{g[8  + o1], g[8  + o1 + 1]});
            a = cmul(a, C2{g[16 + o2], g[16 + o2 + 1]});
            a = cmul(a, C2{g[24 + o3], g[24 + o3 + 1]});
            sL[l][r * LP + c] = make_float2(a.re, a.im);
        }
    }
    __syncthreads();

    // ---- 3a) A = L1*L0, B = L3*L2, C = L5*L4 ----
#pragma unroll
    for (int s = 0; s < 3; ++s) {
        float re = 0.f, im = 0.f;
#pragma unroll
        for (int k = 0; k < 16; ++k) {
            const float2 xk = sL[2 * s + 1][r * LP + k];
            const float2 yk = sL[2 * s][k * LP + c];
            re = __builtin_fmaf(xk.x, yk.x, re); re = __builtin_fmaf(-xk.y, yk.y, re);
            im = __builtin_fmaf(xk.x, yk.y, im); im = __builtin_fmaf( xk.y, yk.x, im);
        }
        sP[s][r * LP + c] = make_float2(re, im);
    }
    __syncthreads();

    // ---- 3b) D = B*A ----
    {
        float re = 0.f, im = 0.f;
#pragma unroll
        for (int k = 0; k < 16; ++k) {
            const float2 xk = sP[1][r * LP + k];
            const float2 yk = sP[0][k * LP + c];
            re = __builtin_fmaf(xk.x, yk.x, re); re = __builtin_fmaf(-xk.y, yk.y, re);
            im = __builtin_fmaf(xk.x, yk.y, im); im = __builtin_fmaf( xk.y, yk.x, im);
        }
        sD[r * LP + c] = make_float2(re, im);
    }
    __syncthreads();

    // ---- 3c) V = C*D, fold (-i)^popcount(c), pack into matvec layout ----
    {
        float re = 0.f, im = 0.f;
#pragma unroll
        for (int k = 0; k < 16; ++k) {
            const float2 xk = sP[2][r * LP + k];
            const float2 yk = sD[k * LP + c];
            re = __builtin_fmaf(xk.x, yk.x, re); re = __builtin_fmaf(-xk.y, yk.y, re);
            im = __builtin_fmaf(xk.x, yk.y, im); im = __builtin_fmaf( xk.y, yk.x, im);
        }
        // multiply by (-i)^popcount(c): 0:(a,b) 1:(b,-a) 2:(-a,-b) 3:(-b,a)
        const int p4 = __popc(c) & 3;
        float wr, wi;
        if      (p4 == 0) { wr = re;  wi = im;  }
        else if (p4 == 1) { wr = im;  wi = -re; }
        else if (p4 == 2) { wr = -re; wi = -im; }
        else              { wr = -im; wi = re;  }
        float* sVf = reinterpret_cast<float*>(sV4);
        reinterpret_cast<float2*>(&sVf[r * 32 + 2 * c])[0] = make_float2(wr, wi);
    }
    __syncthreads();

    // ---- 4) batched matvec + expectation values (proven R2 path) ----
    float ev[EPT][4];
#pragma unroll
    for (int e = 0; e < EPT; ++e)
#pragma unroll
        for (int q = 0; q < 4; ++q) ev[e][q] = 0.f;

#pragma unroll
    for (int rr = 0; rr < 16; ++rr) {
        float4 row[8];
#pragma unroll
        for (int k = 0; k < 8; ++k) row[k] = sV4[rr * 8 + k];
#pragma unroll
        for (int e = 0; e < EPT; ++e) {
            float re = 0.f, im = 0.f;
#pragma unroll
            for (int k = 0; k < 8; ++k) {
                re = __builtin_fmaf(m[e][2 * k],     row[k].x, re);
                im = __builtin_fmaf(m[e][2 * k],     row[k].y, im);
                re = __builtin_fmaf(m[e][2 * k + 1], row[k].z, re);
                im = __builtin_fmaf(m[e][2 * k + 1], row[k].w, im);
            }
            const float p = __builtin_fmaf(re, re, im * im);
            if (rr & 8) ev[e][0] -= p; else ev[e][0] += p;
            if (rr & 4) ev[e][1] -= p; else ev[e][1] += p;
            if (rr & 2) ev[e][2] -= p; else ev[e][2] += p;
            if (rr & 1) ev[e][3] -= p; else ev[e][3] += p;
        }
    }

#pragma unroll
    for (int e = 0; e < EPT; ++e) {
        out[base + e * 256] = make_float4(ev[e][0], ev[e][1], ev[e][2], ev[e][3]);
    }
}

extern "C" void kernel_launch(void* const* d_in, const int* in_sizes, int n_in,
                              void* d_out, int out_size, void* d_ws, size_t ws_size,
                              hipStream_t stream) {
    const float4* x = (const float4*)d_in[0];   // [B,4] f32
    const float*  w = (const float*)d_in[1];    // [6,4,3] f32
    float4* out = (float4*)d_out;               // [B,4] f32

    const int blocks = BATCH / (256 * EPT);     // 512
    qone_kernel<<<blocks, 256, 0, stream>>>(x, w, out);
}